// Round 1
// baseline (392.030 us; speedup 1.0000x reference)
//
#include <hip/hip_runtime.h>

#define BATCH 4
#define CIN   1024
#define CI    256
#define CO    1024
#define NSP   4096

typedef __attribute__((ext_vector_type(8))) short bf16x8;
typedef __attribute__((ext_vector_type(4))) float f32x4;

struct __align__(8) us4 { unsigned short x, y, z, w; };

#define DEVI __device__ __forceinline__

DEVI unsigned short f2bf(float f) {
  union { float f; unsigned u; } un; un.f = f;
  unsigned u = un.u;
  u += 0x7FFFu + ((u >> 16) & 1u);   // RNE
  return (unsigned short)(u >> 16);
}

DEVI void gl2lds16(const void* g, void* l) {
  __builtin_amdgcn_global_load_lds(
      (const __attribute__((address_space(1))) void*)g,
      (__attribute__((address_space(3))) void*)l, 16, 0, 0);
}

DEVI f32x4 mfma16(bf16x8 a, bf16x8 b, f32x4 c) {
  return __builtin_amdgcn_mfma_f32_16x16x32_bf16(a, b, c, 0, 0, 0);
}

// ---------------------------------------------------------------- prep small
__global__ __launch_bounds__(256) void k_prep(
    const float* __restrict__ w_key, const float* __restrict__ w_val,
    const float* __restrict__ w_out,
    const float* __restrict__ gamma, const float* __restrict__ beta,
    const float* __restrict__ mean,  const float* __restrict__ var,
    const float* __restrict__ b_key,
    unsigned short* __restrict__ wkv, unsigned short* __restrict__ wob,
    float* __restrict__ sq, float* __restrict__ bq)
{
  int idx = blockIdx.x * 256 + threadIdx.x;          // 0 .. 524287
  float wv = (idx < 262144) ? w_key[idx] : w_val[idx - 262144];
  wkv[idx] = f2bf(wv);
  if (idx < 262144) wob[idx] = f2bf(w_out[idx]);
  if (idx < 256) {
    float inv = gamma[idx] * rsqrtf(var[idx] + 1e-5f);
    sq[idx] = 0.25f * inv;                            // sqrt(1/16) folded into qk
    bq[idx] = 0.25f * (beta[idx] + (b_key[idx] - mean[idx]) * inv);
  }
}

// ------------------------------------------------------- x transpose -> bf16
__global__ __launch_bounds__(256) void k_xpose(const float* __restrict__ x,
                                               unsigned short* __restrict__ xT)
{
  __shared__ unsigned short tile[64][65];
  int b = blockIdx.z, k0 = blockIdx.y * 64, n0 = blockIdx.x * 64;
  int tid = threadIdx.x;
  int rr = tid >> 4, cc = tid & 15;
  const float* xb = x + ((size_t)b * CIN + k0) * NSP + n0;
#pragma unroll
  for (int p = 0; p < 4; ++p) {
    int row = p * 16 + rr;
    float4 v = *(const float4*)(xb + (size_t)row * NSP + cc * 4);
    tile[row][cc * 4 + 0] = f2bf(v.x);
    tile[row][cc * 4 + 1] = f2bf(v.y);
    tile[row][cc * 4 + 2] = f2bf(v.z);
    tile[row][cc * 4 + 3] = f2bf(v.w);
  }
  __syncthreads();
  unsigned short* xtb = xT + ((size_t)b * NSP + n0) * CIN + k0;
#pragma unroll
  for (int p = 0; p < 4; ++p) {
    int n = p * 16 + rr;
    int kq = cc * 4;
    us4 pk;
    pk.x = tile[kq + 0][n]; pk.y = tile[kq + 1][n];
    pk.z = tile[kq + 2][n]; pk.w = tile[kq + 3][n];
    *(us4*)(xtb + (size_t)n * CIN + kq) = pk;
  }
}

// -------------------------------------------- 128x128 NT GEMM core (bf16)
// A: (M,K) row-major K-contig;  B: (N,K) row-major K-contig.  BK=64.
// LDS tiles [128 rows][8 chunks of 8 bf16], chunk cc stored at cc^(row&7).
template<int KDIM>
DEVI void gemm_core(const unsigned short* __restrict__ Ab,
                    const unsigned short* __restrict__ Bb,
                    unsigned short* ldsA, unsigned short* ldsB,
                    f32x4 acc[4][4], int tid)
{
  const int lane = tid & 63, wave = tid >> 6;
  const int q = lane >> 4, ln = lane & 15;
  const int wm = wave & 1, wn = wave >> 1;

  int aoff[4][2], boff[4][2];
#pragma unroll
  for (int f = 0; f < 4; ++f) {
    int ra = wm * 64 + f * 16 + ln;
    aoff[f][0] = (ra * 8 + ((q)     ^ (ra & 7))) * 8;
    aoff[f][1] = (ra * 8 + ((q + 4) ^ (ra & 7))) * 8;
    int rb = wn * 64 + f * 16 + ln;
    boff[f][0] = (rb * 8 + ((q)     ^ (rb & 7))) * 8;
    boff[f][1] = (rb * 8 + ((q + 4) ^ (rb & 7))) * 8;
  }
  int sgo[4];
#pragma unroll
  for (int i = 0; i < 4; ++i) {
    int s = i * 256 + tid;
    int row = s >> 3;
    int c8 = (s & 7) ^ (row & 7);
    sgo[i] = row * KDIM + c8 * 8;
  }
  for (int k0 = 0; k0 < KDIM; k0 += 64) {
#pragma unroll
    for (int i = 0; i < 4; ++i) {
      gl2lds16(Ab + sgo[i] + k0, ldsA + (i * 256 + wave * 64) * 8);
      gl2lds16(Bb + sgo[i] + k0, ldsB + (i * 256 + wave * 64) * 8);
    }
    __syncthreads();
#pragma unroll
    for (int kk = 0; kk < 2; ++kk) {
      bf16x8 af[4], bfr[4];
#pragma unroll
      for (int f = 0; f < 4; ++f) af[f]  = *(const bf16x8*)(ldsA + aoff[f][kk]);
#pragma unroll
      for (int f = 0; f < 4; ++f) bfr[f] = *(const bf16x8*)(ldsB + boff[f][kk]);
#pragma unroll
      for (int mf = 0; mf < 4; ++mf)
#pragma unroll
        for (int nf = 0; nf < 4; ++nf)
          acc[mf][nf] = mfma16(af[mf], bfr[nf], acc[mf][nf]);
    }
    __syncthreads();
  }
}

// ------------------------------------------------- qk/value conv (fused)
__global__ __launch_bounds__(256) void k_convqkv(
    const unsigned short* __restrict__ wkv,   // [512][1024]
    const unsigned short* __restrict__ xT,    // [B][4096][1024]
    const float* __restrict__ sq, const float* __restrict__ bq,
    const float* __restrict__ bval,
    unsigned short* __restrict__ qkT,         // [B][4096][256]
    unsigned short* __restrict__ vv)          // [B][256][4096]
{
  __shared__ __align__(16) unsigned short ldsA[128 * 64];
  __shared__ __align__(16) unsigned short ldsB[128 * 64];
  int b = blockIdx.z, m0 = blockIdx.y * 128, n0 = blockIdx.x * 128;
  int tid = threadIdx.x;
  f32x4 z = {0.f, 0.f, 0.f, 0.f};
  f32x4 acc[4][4];
#pragma unroll
  for (int i = 0; i < 4; ++i)
#pragma unroll
    for (int j = 0; j < 4; ++j) acc[i][j] = z;

  gemm_core<CIN>(wkv + (size_t)m0 * CIN, xT + ((size_t)b * NSP + n0) * CIN,
                 ldsA, ldsB, acc, tid);

  int lane = tid & 63, wave = tid >> 6, q = lane >> 4, ln = lane & 15;
  int wm = wave & 1, wn = wave >> 1;
  if (m0 < 256) {
#pragma unroll
    for (int mf = 0; mf < 4; ++mf) {
      int cb = m0 + wm * 64 + mf * 16 + q * 4;
      float s0_ = sq[cb + 0], s1_ = sq[cb + 1], s2_ = sq[cb + 2], s3_ = sq[cb + 3];
      float b0_ = bq[cb + 0], b1_ = bq[cb + 1], b2_ = bq[cb + 2], b3_ = bq[cb + 3];
#pragma unroll
      for (int nf = 0; nf < 4; ++nf) {
        int n = n0 + wn * 64 + nf * 16 + ln;
        us4 pk;
        pk.x = f2bf(acc[mf][nf][0] * s0_ + b0_);
        pk.y = f2bf(acc[mf][nf][1] * s1_ + b1_);
        pk.z = f2bf(acc[mf][nf][2] * s2_ + b2_);
        pk.w = f2bf(acc[mf][nf][3] * s3_ + b3_);
        *(us4*)(qkT + ((size_t)b * NSP + n) * CI + cb) = pk;
      }
    }
  } else {
#pragma unroll
    for (int mf = 0; mf < 4; ++mf) {
      int cb = (m0 - 256) + wm * 64 + mf * 16 + q * 4;
#pragma unroll
      for (int r = 0; r < 4; ++r) {
        float bv = bval[cb + r];
#pragma unroll
        for (int nf = 0; nf < 4; ++nf) {
          int n = n0 + wn * 64 + nf * 16 + ln;
          vv[((size_t)b * CI + (cb + r)) * NSP + n] = f2bf(acc[mf][nf][r] + bv);
        }
      }
    }
  }
}

// ------------------------------------------------------ fused attention
__global__ __launch_bounds__(256, 2) void k_attn(
    const unsigned short* __restrict__ qkT,   // [B][4096][256]
    const unsigned short* __restrict__ vv,    // [B][256][4096]
    unsigned short* __restrict__ ctx)         // [B][4096][256]
{
  __shared__ __align__(16) unsigned short Kt[32 * 256];  // [32 j][32 cc] swizzled
  __shared__ __align__(16) unsigned short Vt[256 * 32];  // [256 c][4 cc] swizzled
  __shared__ __align__(16) unsigned short Pl[4 * 512];   // per-wave [16 m][4 cc]

  int bid = blockIdx.x;                       // 256 blocks
  int b  = (bid & 7) >> 1;                    // XCD-friendly: 2 XCDs per batch
  int qt = ((bid >> 3) << 1) | (bid & 1);
  int n0 = qt * 64;
  int tid = threadIdx.x, lane = tid & 63, wave = tid >> 6;
  int q = lane >> 4, ln = lane & 15;
  const unsigned short* qkb = qkT + (size_t)b * NSP * CI;
  const unsigned short* vb  = vv  + (size_t)b * CI * NSP;

  // Q fragments in registers: wave's 16 q-rows, all 256 channels
  bf16x8 Qf[8];
  {
    const unsigned short* qrow = qkb + (size_t)(n0 + wave * 16 + ln) * CI + q * 8;
#pragma unroll
    for (int t = 0; t < 8; ++t) Qf[t] = *(const bf16x8*)(qrow + t * 32);
  }

  int koff[2][8];
#pragma unroll
  for (int js = 0; js < 2; ++js) {
    int j = js * 16 + ln;
#pragma unroll
    for (int t = 0; t < 8; ++t) {
      int cc = t * 4 + q;
      koff[js][t] = (j * 32 + ((cc & 24) | ((cc ^ j) & 7))) * 8;
    }
  }
  int voff[16];
#pragma unroll
  for (int cf = 0; cf < 16; ++cf) {
    int c = cf * 16 + ln;
    voff[cf] = (c * 4 + ((q ^ (c >> 1)) & 3)) * 8;
  }
  int proff = wave * 512 + (ln * 4 + ((q ^ (ln >> 1)) & 3)) * 8;
  int pw[2][4];
#pragma unroll
  for (int js = 0; js < 2; ++js)
#pragma unroll
    for (int r = 0; r < 4; ++r) {
      int m = q * 4 + r;
      int j = js * 16 + ln;
      int cc = j >> 3;
      pw[js][r] = wave * 512 + (m * 4 + ((cc ^ (m >> 1)) & 3)) * 8 + (j & 7);
    }

  int gko[4], gvo[4];
#pragma unroll
  for (int i = 0; i < 4; ++i) {
    int s = i * 256 + tid;
    int j = s >> 5, f = s & 31;
    gko[i] = j * CI + ((f & 24) | ((f ^ j) & 7)) * 8;
    int c = s >> 2;
    gvo[i] = c * NSP + ((s ^ (c >> 1)) & 3) * 8;
  }

  f32x4 O[16];
  f32x4 z = {0.f, 0.f, 0.f, 0.f};
#pragma unroll
  for (int cf = 0; cf < 16; ++cf) O[cf] = z;
  float mrow[4] = {-1e30f, -1e30f, -1e30f, -1e30f};
  float lrow[4] = {0.f, 0.f, 0.f, 0.f};

  for (int j0 = 0; j0 < NSP; j0 += 32) {
#pragma unroll
    for (int i = 0; i < 4; ++i)
      gl2lds16(qkb + (size_t)j0 * CI + gko[i], Kt + (i * 256 + wave * 64) * 8);
#pragma unroll
    for (int i = 0; i < 4; ++i)
      gl2lds16(vb + j0 + gvo[i], Vt + (i * 256 + wave * 64) * 8);
    __syncthreads();

    f32x4 s0 = z, s1 = z;
#pragma unroll
    for (int t = 0; t < 8; ++t) {
      bf16x8 kf0 = *(const bf16x8*)(Kt + koff[0][t]);
      bf16x8 kf1 = *(const bf16x8*)(Kt + koff[1][t]);
      s0 = mfma16(Qf[t], kf0, s0);
      s1 = mfma16(Qf[t], kf1, s1);
    }

    float alr[4];
#pragma unroll
    for (int r = 0; r < 4; ++r) {
      float v0 = s0[r], v1 = s1[r];
      float mx = fmaxf(v0, v1);
      mx = fmaxf(mx, __shfl_xor(mx, 1));
      mx = fmaxf(mx, __shfl_xor(mx, 2));
      mx = fmaxf(mx, __shfl_xor(mx, 4));
      mx = fmaxf(mx, __shfl_xor(mx, 8));
      float mnew = fmaxf(mrow[r], mx);
      float p0 = __expf(v0 - mnew);
      float p1 = __expf(v1 - mnew);
      float al = __expf(mrow[r] - mnew);
      float sm = p0 + p1;
      sm += __shfl_xor(sm, 1);
      sm += __shfl_xor(sm, 2);
      sm += __shfl_xor(sm, 4);
      sm += __shfl_xor(sm, 8);
      lrow[r] = lrow[r] * al + sm;
      mrow[r] = mnew;
      alr[r] = al;
      Pl[pw[0][r]] = f2bf(p0);
      Pl[pw[1][r]] = f2bf(p1);
    }
    f32x4 alv = {alr[0], alr[1], alr[2], alr[3]};
#pragma unroll
    for (int cf = 0; cf < 16; ++cf) O[cf] *= alv;

    bf16x8 pf = *(const bf16x8*)(Pl + proff);
#pragma unroll
    for (int cf = 0; cf < 16; ++cf) {
      bf16x8 vf = *(const bf16x8*)(Vt + voff[cf]);
      O[cf] = mfma16(pf, vf, O[cf]);
    }
    __syncthreads();
  }

  int nq = n0 + wave * 16;
#pragma unroll
  for (int r = 0; r < 4; ++r) {
    float inv = 1.0f / lrow[r];
    unsigned short* crow = ctx + ((size_t)b * NSP + nq + q * 4 + r) * CI + ln;
#pragma unroll
    for (int cf = 0; cf < 16; ++cf)
      crow[cf * 16] = f2bf(O[cf][r] * inv);
  }
}

// ------------------------------------------------------ output conv
__global__ __launch_bounds__(256) void k_convout(
    const unsigned short* __restrict__ wo,    // [1024][256]
    const unsigned short* __restrict__ ctx,   // [B][4096][256]
    const float* __restrict__ bout,
    float* __restrict__ out)                  // [B][1024][4096]
{
  __shared__ __align__(16) unsigned short ldsA[128 * 64];
  __shared__ __align__(16) unsigned short ldsB[128 * 64];
  int b = blockIdx.z, m0 = blockIdx.y * 128, n0 = blockIdx.x * 128;
  int tid = threadIdx.x;
  f32x4 z = {0.f, 0.f, 0.f, 0.f};
  f32x4 acc[4][4];
#pragma unroll
  for (int i = 0; i < 4; ++i)
#pragma unroll
    for (int j = 0; j < 4; ++j) acc[i][j] = z;

  gemm_core<CI>(wo + (size_t)m0 * CI, ctx + ((size_t)b * NSP + n0) * CI,
                ldsA, ldsB, acc, tid);

  int lane = tid & 63, wave = tid >> 6, q = lane >> 4, ln = lane & 15;
  int wm = wave & 1, wn = wave >> 1;
#pragma unroll
  for (int mf = 0; mf < 4; ++mf) {
    int cb = m0 + wm * 64 + mf * 16 + q * 4;
    float bo0 = bout[cb + 0], bo1 = bout[cb + 1], bo2 = bout[cb + 2], bo3 = bout[cb + 3];
#pragma unroll
    for (int nf = 0; nf < 4; ++nf) {
      int n = n0 + wn * 64 + nf * 16 + ln;
      float* p = out + ((size_t)b * CO + cb) * NSP + n;
      p[0 * (size_t)NSP] = acc[mf][nf][0] + bo0;
      p[1 * (size_t)NSP] = acc[mf][nf][1] + bo1;
      p[2 * (size_t)NSP] = acc[mf][nf][2] + bo2;
      p[3 * (size_t)NSP] = acc[mf][nf][3] + bo3;
    }
  }
}

// ---------------------------------------------------------------- launch
extern "C" void kernel_launch(void* const* d_in, const int* in_sizes, int n_in,
                              void* d_out, int out_size, void* d_ws, size_t ws_size,
                              hipStream_t stream) {
  const float* x     = (const float*)d_in[0];
  const float* w_key = (const float*)d_in[1];
  const float* b_key = (const float*)d_in[2];
  const float* gamma = (const float*)d_in[3];
  const float* beta  = (const float*)d_in[4];
  const float* mean  = (const float*)d_in[5];
  const float* var   = (const float*)d_in[6];
  const float* w_val = (const float*)d_in[7];
  const float* b_val = (const float*)d_in[8];
  const float* w_out = (const float*)d_in[9];
  const float* b_out = (const float*)d_in[10];
  float* out = (float*)d_out;

  char* ws = (char*)d_ws;
  unsigned short* xT  = (unsigned short*)(ws);               // 32 MiB
  unsigned short* wkv = (unsigned short*)(ws + 33554432);    // 1 MiB
  unsigned short* wob = (unsigned short*)(ws + 34603008);    // 512 KiB
  unsigned short* qkT = (unsigned short*)(ws + 35127296);    // 8 MiB
  unsigned short* vv  = (unsigned short*)(ws + 43515904);    // 8 MiB
  unsigned short* ctx = (unsigned short*)(ws + 51904512);    // 8 MiB
  float* sq = (float*)(ws + 60293120);                       // 1 KiB
  float* bq = (float*)(ws + 60294144);                       // 1 KiB

  k_prep<<<2048, 256, 0, stream>>>(w_key, w_val, w_out, gamma, beta, mean, var,
                                   b_key, wkv, wob, sq, bq);
  k_xpose<<<dim3(64, 16, 4), 256, 0, stream>>>(x, xT);
  k_convqkv<<<dim3(32, 4, 4), 256, 0, stream>>>(wkv, xT, sq, bq, b_val, qkT, vv);
  k_attn<<<256, 256, 0, stream>>>(qkT, vv, ctx);
  k_convout<<<dim3(32, 8, 4), 256, 0, stream>>>(wob, ctx, b_out, out);
}